// Round 1
// baseline (8524.174 us; speedup 1.0000x reference)
//
#include <hip/hip_runtime.h>

#define HID 128
#define GROWS 16

// ---------------- degree / normalization ----------------

__global__ void k_deg_init(float* __restrict__ dinv, int N) {
    int i = blockIdx.x * 256 + threadIdx.x;
    if (i < N) dinv[i] = 1.0f;   // self-loop contributes 1
}

__global__ void k_deg_count(const int* __restrict__ col, float* __restrict__ dinv, int E) {
    int e = blockIdx.x * 256 + threadIdx.x;
    if (e < E) atomicAdd(&dinv[col[e]], 1.0f);   // integer sums in f32: exact, order-independent
}

__global__ void k_deg_rsqrt(float* __restrict__ dinv, int N) {
    int i = blockIdx.x * 256 + threadIdx.x;
    if (i < N) dinv[i] = 1.0f / sqrtf(dinv[i]);
}

// ---------------- GEMM: H = act(X) @ W  (act = optional ReLU on input) ----------------
// W: [128 x 128] row-major (k-major), staged fully in LDS (64 KB).
// Block: 256 threads handles GROWS=16 rows. Thread t -> row (t>>4), cols (t&15)*8 .. +7.

__global__ __launch_bounds__(256) void k_gemm(const float* __restrict__ X,
                                              const float* __restrict__ W,
                                              float* __restrict__ H,
                                              int N, int relu_in) {
    __shared__ float Ws[HID * HID];
    __shared__ float Xs[GROWS][HID];
    const int t = threadIdx.x;

    // stage W (16384 floats = 4096 float4)
    for (int i = t; i < HID * HID / 4; i += 256)
        reinterpret_cast<float4*>(Ws)[i] = reinterpret_cast<const float4*>(W)[i];

    // stage X tile (16 rows x 128 = 512 float4), fuse ReLU of previous layer
    const int row0 = blockIdx.x * GROWS;
    for (int i = t; i < GROWS * HID / 4; i += 256) {
        int r = i >> 5;        // 32 float4 per row
        int cc = i & 31;
        int gr = row0 + r;
        float4 v = make_float4(0.f, 0.f, 0.f, 0.f);
        if (gr < N) {
            v = reinterpret_cast<const float4*>(X + (size_t)gr * HID)[cc];
            if (relu_in) {
                v.x = fmaxf(v.x, 0.f); v.y = fmaxf(v.y, 0.f);
                v.z = fmaxf(v.z, 0.f); v.w = fmaxf(v.w, 0.f);
            }
        }
        reinterpret_cast<float4*>(&Xs[r][0])[cc] = v;
    }
    __syncthreads();

    const int r  = t >> 4;
    const int c0 = (t & 15) * 8;
    float acc[8] = {0.f, 0.f, 0.f, 0.f, 0.f, 0.f, 0.f, 0.f};

#pragma unroll 4
    for (int k = 0; k < HID; ++k) {
        float xv = Xs[r][k];
        const float4 w0 = *reinterpret_cast<const float4*>(&Ws[k * HID + c0]);
        const float4 w1 = *reinterpret_cast<const float4*>(&Ws[k * HID + c0 + 4]);
        acc[0] = fmaf(xv, w0.x, acc[0]);
        acc[1] = fmaf(xv, w0.y, acc[1]);
        acc[2] = fmaf(xv, w0.z, acc[2]);
        acc[3] = fmaf(xv, w0.w, acc[3]);
        acc[4] = fmaf(xv, w1.x, acc[4]);
        acc[5] = fmaf(xv, w1.y, acc[5]);
        acc[6] = fmaf(xv, w1.z, acc[6]);
        acc[7] = fmaf(xv, w1.w, acc[7]);
    }

    const int gr = row0 + r;
    if (gr < N) {
        float4* o = reinterpret_cast<float4*>(H + (size_t)gr * HID + c0);
        o[0] = make_float4(acc[0], acc[1], acc[2], acc[3]);
        o[1] = make_float4(acc[4], acc[5], acc[6], acc[7]);
    }
}

// ---------------- aggregation ----------------
// init: out[i][c] = dinv[i]^2 * h[i][c] + bias[c]   (self-loop + bias; fully overwrites out)
__global__ void k_agg_init(const float* __restrict__ h, const float* __restrict__ dinv,
                           const float* __restrict__ bias, float* __restrict__ out, int N) {
    int i = blockIdx.x * 256 + threadIdx.x;        // one float4 each
    if (i >= N * (HID / 4)) return;
    int node = i >> 5;
    int cc   = i & 31;
    float d = dinv[node];
    float s = d * d;
    float4 hv = reinterpret_cast<const float4*>(h)[i];
    float4 bv = reinterpret_cast<const float4*>(bias)[cc];
    float4 o = make_float4(fmaf(s, hv.x, bv.x), fmaf(s, hv.y, bv.y),
                           fmaf(s, hv.z, bv.z), fmaf(s, hv.w, bv.w));
    reinterpret_cast<float4*>(out)[i] = o;
}

// edges: out[col] += dinv[row]*dinv[col] * h[row]; 32 lanes per edge, float4 per lane
__global__ void k_agg_edges(const float* __restrict__ h, const int* __restrict__ row,
                            const int* __restrict__ col, const float* __restrict__ dinv,
                            float* __restrict__ out, int E) {
    int tid = blockIdx.x * 256 + threadIdx.x;
    int e = tid >> 5;
    if (e >= E) return;
    int lane = tid & 31;
    int r = row[e];
    int c = col[e];
    float norm = dinv[r] * dinv[c];
    const float4 hv = *reinterpret_cast<const float4*>(h + (size_t)r * HID + lane * 4);
    float* op = out + (size_t)c * HID + lane * 4;
    atomicAdd(op + 0, norm * hv.x);
    atomicAdd(op + 1, norm * hv.y);
    atomicAdd(op + 2, norm * hv.z);
    atomicAdd(op + 3, norm * hv.w);
}

// ---------------- launch ----------------

extern "C" void kernel_launch(void* const* d_in, const int* in_sizes, int n_in,
                              void* d_out, int out_size, void* d_ws, size_t ws_size,
                              hipStream_t stream) {
    const float* x  = (const float*)d_in[0];
    const int*   ei = (const int*)  d_in[1];
    const float* W0 = (const float*)d_in[2];
    const float* b0 = (const float*)d_in[3];
    const float* W1 = (const float*)d_in[4];
    const float* b1 = (const float*)d_in[5];
    const float* W2 = (const float*)d_in[6];
    const float* b2 = (const float*)d_in[7];

    const int N = in_sizes[0] / HID;
    const int E = in_sizes[1] / 2;
    const int* row = ei;        // edge_index[0] = sources
    const int* col = ei + E;    // edge_index[1] = destinations

    float* hbuf = (float*)d_ws;                       // [N,128]
    float* dinv = hbuf + (size_t)N * HID;             // [N]
    float* out  = (float*)d_out;                      // [N,128], also inter-layer activation

    const int nb_n    = (N + 255) / 256;
    const int nb_e    = (E + 255) / 256;
    const int nb_init = (N * (HID / 4) + 255) / 256;
    const int nb_edge = (E * 32 + 255) / 256;         // 32 lanes per edge
    const int nb_gemm = (N + GROWS - 1) / GROWS;

    // degrees -> dinv
    k_deg_init <<<nb_n, 256, 0, stream>>>(dinv, N);
    k_deg_count<<<nb_e, 256, 0, stream>>>(col, dinv, E);
    k_deg_rsqrt<<<nb_n, 256, 0, stream>>>(dinv, N);

    // layer 0: h = x @ W0 ; out = A_norm h + b0
    k_gemm     <<<nb_gemm, 256, 0, stream>>>(x, W0, hbuf, N, 0);
    k_agg_init <<<nb_init, 256, 0, stream>>>(hbuf, dinv, b0, out, N);
    k_agg_edges<<<nb_edge, 256, 0, stream>>>(hbuf, row, col, dinv, out, E);

    // layer 1: h = relu(out) @ W1 ; out = A_norm h + b1
    k_gemm     <<<nb_gemm, 256, 0, stream>>>(out, W1, hbuf, N, 1);
    k_agg_init <<<nb_init, 256, 0, stream>>>(hbuf, dinv, b1, out, N);
    k_agg_edges<<<nb_edge, 256, 0, stream>>>(hbuf, row, col, dinv, out, E);

    // layer 2: h = relu(out) @ W2 ; out = A_norm h + b2
    k_gemm     <<<nb_gemm, 256, 0, stream>>>(out, W2, hbuf, N, 1);
    k_agg_init <<<nb_init, 256, 0, stream>>>(hbuf, dinv, b2, out, N);
    k_agg_edges<<<nb_edge, 256, 0, stream>>>(hbuf, row, col, dinv, out, E);
}

// Round 2
// 1055.246 us; speedup vs baseline: 8.0779x; 8.0779x over previous
//
#include <hip/hip_runtime.h>

#define HID 128
#define GROWS 16

// ================= degree / normalization / CSR build =================

__global__ void k_deg_count(const int* __restrict__ col, int* __restrict__ cnt, int E) {
    int e = blockIdx.x * 256 + threadIdx.x;
    if (e < E) atomicAdd(&cnt[col[e]], 1);
}

__global__ void k_dinv(const int* __restrict__ cnt, float* __restrict__ dinv, int N) {
    int i = blockIdx.x * 256 + threadIdx.x;
    if (i < N) dinv[i] = rsqrtf((float)(cnt[i] + 1));   // +1 = self-loop
}

// exclusive scan, stage 1: per-256-block Hillis-Steele; writes exclusive partials + block sums
__global__ void k_scan_block(const int* __restrict__ cnt, int* __restrict__ excl,
                             int* __restrict__ bsum, int N) {
    __shared__ int s[256];
    int i = blockIdx.x * 256 + threadIdx.x;
    int v = (i < N) ? cnt[i] : 0;
    s[threadIdx.x] = v;
    __syncthreads();
    for (int off = 1; off < 256; off <<= 1) {
        int t = (threadIdx.x >= off) ? s[threadIdx.x - off] : 0;
        __syncthreads();
        s[threadIdx.x] += t;
        __syncthreads();
    }
    if (i < N) excl[i] = s[threadIdx.x] - v;
    if (threadIdx.x == 255) bsum[blockIdx.x] = s[255];
}

// stage 2: single block scans the <=1024 block sums (exclusive, in place)
__global__ __launch_bounds__(1024) void k_scan_bsum(int* __restrict__ bsum, int nb) {
    __shared__ int s[1024];
    int i = threadIdx.x;
    int v = (i < nb) ? bsum[i] : 0;
    s[i] = v;
    __syncthreads();
    for (int off = 1; off < 1024; off <<= 1) {
        int t = (i >= off) ? s[i - off] : 0;
        __syncthreads();
        s[i] += t;
        __syncthreads();
    }
    if (i < nb) bsum[i] = s[i] - v;
}

// stage 3: add block offsets; thread 0 writes row_ptr[N] = E
__global__ void k_scan_add(int* __restrict__ row_ptr, const int* __restrict__ bsum,
                           int N, int E) {
    int i = blockIdx.x * 256 + threadIdx.x;
    if (i < N) row_ptr[i] += bsum[blockIdx.x];
    if (i == 0) row_ptr[N] = E;
}

// fill CSR src lists (order within a node nondeterministic: permutes f32 summands only)
__global__ void k_fill(const int* __restrict__ row, const int* __restrict__ col,
                       const int* __restrict__ row_ptr, int* __restrict__ fill,
                       int* __restrict__ csr_src, int E) {
    int e = blockIdx.x * 256 + threadIdx.x;
    if (e < E) {
        int c = col[e];
        int p = row_ptr[c] + atomicAdd(&fill[c], 1);
        csr_src[p] = row[e];
    }
}

// ================= GEMM: H = act(X) @ W =================
// W [128x128] staged in LDS; 256 threads = 16 rows, thread -> (row t>>4, 8 cols)

__global__ __launch_bounds__(256) void k_gemm(const float* __restrict__ X,
                                              const float* __restrict__ W,
                                              float* __restrict__ H,
                                              int N, int relu_in) {
    __shared__ float Ws[HID * HID];
    __shared__ float Xs[GROWS][HID];
    const int t = threadIdx.x;

    for (int i = t; i < HID * HID / 4; i += 256)
        reinterpret_cast<float4*>(Ws)[i] = reinterpret_cast<const float4*>(W)[i];

    const int row0 = blockIdx.x * GROWS;
    for (int i = t; i < GROWS * HID / 4; i += 256) {
        int r = i >> 5;
        int cc = i & 31;
        int gr = row0 + r;
        float4 v = make_float4(0.f, 0.f, 0.f, 0.f);
        if (gr < N) {
            v = reinterpret_cast<const float4*>(X + (size_t)gr * HID)[cc];
            if (relu_in) {
                v.x = fmaxf(v.x, 0.f); v.y = fmaxf(v.y, 0.f);
                v.z = fmaxf(v.z, 0.f); v.w = fmaxf(v.w, 0.f);
            }
        }
        reinterpret_cast<float4*>(&Xs[r][0])[cc] = v;
    }
    __syncthreads();

    const int r  = t >> 4;
    const int c0 = (t & 15) * 8;
    float acc[8] = {0.f, 0.f, 0.f, 0.f, 0.f, 0.f, 0.f, 0.f};

#pragma unroll 4
    for (int k = 0; k < HID; ++k) {
        float xv = Xs[r][k];
        const float4 w0 = *reinterpret_cast<const float4*>(&Ws[k * HID + c0]);
        const float4 w1 = *reinterpret_cast<const float4*>(&Ws[k * HID + c0 + 4]);
        acc[0] = fmaf(xv, w0.x, acc[0]);
        acc[1] = fmaf(xv, w0.y, acc[1]);
        acc[2] = fmaf(xv, w0.z, acc[2]);
        acc[3] = fmaf(xv, w0.w, acc[3]);
        acc[4] = fmaf(xv, w1.x, acc[4]);
        acc[5] = fmaf(xv, w1.y, acc[5]);
        acc[6] = fmaf(xv, w1.z, acc[6]);
        acc[7] = fmaf(xv, w1.w, acc[7]);
    }

    const int gr = row0 + r;
    if (gr < N) {
        float4* o = reinterpret_cast<float4*>(H + (size_t)gr * HID + c0);
        o[0] = make_float4(acc[0], acc[1], acc[2], acc[3]);
        o[1] = make_float4(acc[4], acc[5], acc[6], acc[7]);
    }
}

// ================= aggregation (gather, no atomics) =================
// 1 wave per node; lane owns 2 cols (float2). out = di*(sum_j dinv[s_j]*h[s_j] + di*h[node]) + b

__global__ __launch_bounds__(256) void k_agg_csr(const float* __restrict__ h,
                                                 const int* __restrict__ csr_src,
                                                 const int* __restrict__ row_ptr,
                                                 const float* __restrict__ dinv,
                                                 const float* __restrict__ bias,
                                                 float* __restrict__ out, int N) {
    int node = (blockIdx.x * 256 + threadIdx.x) >> 6;
    if (node >= N) return;
    int lane = threadIdx.x & 63;
    int c = lane * 2;

    float di = dinv[node];
    const float2 hself = *reinterpret_cast<const float2*>(h + (size_t)node * HID + c);
    float accx = di * hself.x;
    float accy = di * hself.y;

    int beg = row_ptr[node];
    int end = row_ptr[node + 1];
    for (int j = beg; j < end; ++j) {
        int s = csr_src[j];
        float ds = dinv[s];
        const float2 hv = *reinterpret_cast<const float2*>(h + (size_t)s * HID + c);
        accx = fmaf(ds, hv.x, accx);
        accy = fmaf(ds, hv.y, accy);
    }

    float2 o;
    o.x = fmaf(di, accx, bias[c]);
    o.y = fmaf(di, accy, bias[c + 1]);
    *reinterpret_cast<float2*>(out + (size_t)node * HID + c) = o;
}

// ================= launch =================

extern "C" void kernel_launch(void* const* d_in, const int* in_sizes, int n_in,
                              void* d_out, int out_size, void* d_ws, size_t ws_size,
                              hipStream_t stream) {
    const float* x  = (const float*)d_in[0];
    const int*   ei = (const int*)  d_in[1];
    const float* W0 = (const float*)d_in[2];
    const float* b0 = (const float*)d_in[3];
    const float* W1 = (const float*)d_in[4];
    const float* b1 = (const float*)d_in[5];
    const float* W2 = (const float*)d_in[6];
    const float* b2 = (const float*)d_in[7];

    const int N = in_sizes[0] / HID;
    const int E = in_sizes[1] / 2;
    const int* row = ei;        // sources
    const int* col = ei + E;    // destinations

    const int nb_n = (N + 255) / 256;

    // workspace layout (all 4-byte elems)
    float* hbuf    = (float*)d_ws;                    // [N,128]
    float* dinv    = hbuf + (size_t)N * HID;          // [N]
    int*   cnt     = (int*)(dinv + N);                // [N]
    int*   row_ptr = cnt + N;                         // [N+1]
    int*   fill    = row_ptr + (N + 1);               // [N]
    int*   bsum    = fill + N;                        // [nb_n]
    int*   csr_src = bsum + nb_n;                     // [E]
    float* out     = (float*)d_out;                   // [N,128]

    const int nb_e    = (E + 255) / 256;
    const int nb_gemm = (N + GROWS - 1) / GROWS;
    const int nb_agg  = (N * 64 + 255) / 256;         // 1 wave per node

    // ---- CSR build (every call; deterministic work) ----
    hipMemsetAsync(cnt,  0, (size_t)N * sizeof(int), stream);
    hipMemsetAsync(fill, 0, (size_t)N * sizeof(int), stream);
    k_deg_count<<<nb_e, 256, 0, stream>>>(col, cnt, E);
    k_dinv     <<<nb_n, 256, 0, stream>>>(cnt, dinv, N);
    k_scan_block<<<nb_n, 256, 0, stream>>>(cnt, row_ptr, bsum, N);
    k_scan_bsum <<<1, 1024, 0, stream>>>(bsum, nb_n);
    k_scan_add  <<<nb_n, 256, 0, stream>>>(row_ptr, bsum, N, E);
    k_fill      <<<nb_e, 256, 0, stream>>>(row, col, row_ptr, fill, csr_src, E);

    // ---- layer 0 ----
    k_gemm   <<<nb_gemm, 256, 0, stream>>>(x, W0, hbuf, N, 0);
    k_agg_csr<<<nb_agg, 256, 0, stream>>>(hbuf, csr_src, row_ptr, dinv, b0, out, N);
    // ---- layer 1 ----
    k_gemm   <<<nb_gemm, 256, 0, stream>>>(out, W1, hbuf, N, 1);
    k_agg_csr<<<nb_agg, 256, 0, stream>>>(hbuf, csr_src, row_ptr, dinv, b1, out, N);
    // ---- layer 2 ----
    k_gemm   <<<nb_gemm, 256, 0, stream>>>(out, W2, hbuf, N, 1);
    k_agg_csr<<<nb_agg, 256, 0, stream>>>(hbuf, csr_src, row_ptr, dinv, b2, out, N);
}

// Round 3
// 852.215 us; speedup vs baseline: 10.0024x; 1.2382x over previous
//
#include <hip/hip_runtime.h>

#define HID 128
#define BR  128   // GEMM rows per block

// ================= degree / normalization / CSR build =================

__global__ void k_deg_count(const int* __restrict__ col, int* __restrict__ cnt, int E) {
    int e = blockIdx.x * 256 + threadIdx.x;
    if (e < E) atomicAdd(&cnt[col[e]], 1);
}

__global__ void k_dinv(const int* __restrict__ cnt, float* __restrict__ dinv, int N) {
    int i = blockIdx.x * 256 + threadIdx.x;
    if (i < N) dinv[i] = 1.0f / sqrtf((float)(cnt[i] + 1));   // +1 = self-loop
}

__global__ void k_scan_block(const int* __restrict__ cnt, int* __restrict__ excl,
                             int* __restrict__ bsum, int N) {
    __shared__ int s[256];
    int i = blockIdx.x * 256 + threadIdx.x;
    int v = (i < N) ? cnt[i] : 0;
    s[threadIdx.x] = v;
    __syncthreads();
    for (int off = 1; off < 256; off <<= 1) {
        int t = (threadIdx.x >= off) ? s[threadIdx.x - off] : 0;
        __syncthreads();
        s[threadIdx.x] += t;
        __syncthreads();
    }
    if (i < N) excl[i] = s[threadIdx.x] - v;
    if (threadIdx.x == 255) bsum[blockIdx.x] = s[255];
}

__global__ __launch_bounds__(1024) void k_scan_bsum(int* __restrict__ bsum, int nb) {
    __shared__ int s[1024];
    int i = threadIdx.x;
    int v = (i < nb) ? bsum[i] : 0;
    s[i] = v;
    __syncthreads();
    for (int off = 1; off < 1024; off <<= 1) {
        int t = (i >= off) ? s[i - off] : 0;
        __syncthreads();
        s[i] += t;
        __syncthreads();
    }
    if (i < nb) bsum[i] = s[i] - v;
}

__global__ void k_scan_add(int* __restrict__ row_ptr, const int* __restrict__ bsum,
                           int N, int E) {
    int i = blockIdx.x * 256 + threadIdx.x;
    if (i < N) row_ptr[i] += bsum[blockIdx.x];
    if (i == 0) row_ptr[N] = E;
}

__global__ void k_fill(const int* __restrict__ row, const int* __restrict__ col,
                       const int* __restrict__ row_ptr, int* __restrict__ fill,
                       int* __restrict__ csr_src, int E) {
    int e = blockIdx.x * 256 + threadIdx.x;
    if (e < E) {
        int c = col[e];
        int p = row_ptr[c] + atomicAdd(&fill[c], 1);
        csr_src[p] = row[e];
    }
}

// ================= GEMM: H = dinv .* (act(X) @ W) =================
// 256 threads, 128-row tile. Thread (rg,cg) owns 8 rows x 8 cols (64 acc).
// Xs columns XOR-swizzled by (rg&3)<<3 so the 8 per-k X reads are conflict-free.

__global__ __launch_bounds__(256, 1) void k_gemm(const float* __restrict__ X,
                                                 const float* __restrict__ W,
                                                 const float* __restrict__ dinv,
                                                 float* __restrict__ H,
                                                 int N, int relu_in) {
    __shared__ float Ws[HID * HID];   // 64 KB
    __shared__ float Xs[BR * HID];    // 64 KB, swizzled cols
    const int t = threadIdx.x;
    const int row0 = blockIdx.x * BR;

    // stage W: 4096 float4
    for (int i = t; i < HID * HID / 4; i += 256)
        reinterpret_cast<float4*>(Ws)[i] = reinterpret_cast<const float4*>(W)[i];

    // stage X tile: 128 rows x 32 float4, ReLU fused, columns swizzled
    for (int i = t; i < BR * HID / 4; i += 256) {
        int r = i >> 5, cc = i & 31;
        int gr = row0 + r;
        float4 v = make_float4(0.f, 0.f, 0.f, 0.f);
        if (gr < N) {
            v = reinterpret_cast<const float4*>(X + (size_t)gr * HID)[cc];
            if (relu_in) {
                v.x = fmaxf(v.x, 0.f); v.y = fmaxf(v.y, 0.f);
                v.z = fmaxf(v.z, 0.f); v.w = fmaxf(v.w, 0.f);
            }
        }
        int col = (cc * 4) ^ (((r >> 3) & 3) << 3);
        *reinterpret_cast<float4*>(&Xs[r * HID + col]) = v;
    }
    __syncthreads();

    const int rg = t >> 4;            // 0..15
    const int cg = t & 15;            // 0..15
    const int r0 = rg * 8;
    const int c0 = cg * 8;
    const int swz = (rg & 3) << 3;    // per-thread constant; (r0+i)>>3 == rg for i<8

    float acc[8][8];
#pragma unroll
    for (int i = 0; i < 8; ++i)
#pragma unroll
        for (int j = 0; j < 8; ++j) acc[i][j] = 0.f;

#pragma unroll 2
    for (int k = 0; k < HID; ++k) {
        const int kk = k ^ swz;
        float xv[8];
#pragma unroll
        for (int i = 0; i < 8; ++i) xv[i] = Xs[(r0 + i) * HID + kk];
        const float4 w0 = *reinterpret_cast<const float4*>(&Ws[k * HID + c0]);
        const float4 w1 = *reinterpret_cast<const float4*>(&Ws[k * HID + c0 + 4]);
        const float wv[8] = {w0.x, w0.y, w0.z, w0.w, w1.x, w1.y, w1.z, w1.w};
#pragma unroll
        for (int i = 0; i < 8; ++i)
#pragma unroll
            for (int j = 0; j < 8; ++j)
                acc[i][j] = fmaf(xv[i], wv[j], acc[i][j]);
    }

#pragma unroll
    for (int i = 0; i < 8; ++i) {
        int gr = row0 + r0 + i;
        if (gr < N) {
            float d = dinv[gr];
            float4 o0 = make_float4(acc[i][0] * d, acc[i][1] * d, acc[i][2] * d, acc[i][3] * d);
            float4 o1 = make_float4(acc[i][4] * d, acc[i][5] * d, acc[i][6] * d, acc[i][7] * d);
            float4* o = reinterpret_cast<float4*>(H + (size_t)gr * HID + c0);
            o[0] = o0;
            o[1] = o1;
        }
    }
}

// ================= aggregation (gather, pre-scaled h', unroll 4) =================
// h' rows already carry dinv[src]; out[i] = dinv[i]*(h'[i] + sum_j h'[src_j]) + b

__global__ __launch_bounds__(256) void k_agg_csr(const float* __restrict__ h,
                                                 const int* __restrict__ csr_src,
                                                 const int* __restrict__ row_ptr,
                                                 const float* __restrict__ dinv,
                                                 const float* __restrict__ bias,
                                                 float* __restrict__ out, int N) {
    int node = (blockIdx.x * 256 + threadIdx.x) >> 6;
    if (node >= N) return;
    int lane = threadIdx.x & 63;
    int c = lane * 2;

    const float2 hs = *reinterpret_cast<const float2*>(h + (size_t)node * HID + c);
    float accx = hs.x, accy = hs.y;

    int j = row_ptr[node];
    const int end = row_ptr[node + 1];

    for (; j + 4 <= end; j += 4) {
        int s0 = csr_src[j];
        int s1 = csr_src[j + 1];
        int s2 = csr_src[j + 2];
        int s3 = csr_src[j + 3];
        float2 h0 = *reinterpret_cast<const float2*>(h + (size_t)s0 * HID + c);
        float2 h1 = *reinterpret_cast<const float2*>(h + (size_t)s1 * HID + c);
        float2 h2 = *reinterpret_cast<const float2*>(h + (size_t)s2 * HID + c);
        float2 h3 = *reinterpret_cast<const float2*>(h + (size_t)s3 * HID + c);
        accx += (h0.x + h1.x) + (h2.x + h3.x);
        accy += (h0.y + h1.y) + (h2.y + h3.y);
    }
    for (; j < end; ++j) {
        int s = csr_src[j];
        float2 hv = *reinterpret_cast<const float2*>(h + (size_t)s * HID + c);
        accx += hv.x;
        accy += hv.y;
    }

    float di = dinv[node];
    float2 o;
    o.x = fmaf(di, accx, bias[c]);
    o.y = fmaf(di, accy, bias[c + 1]);
    *reinterpret_cast<float2*>(out + (size_t)node * HID + c) = o;
}

// ================= launch =================

extern "C" void kernel_launch(void* const* d_in, const int* in_sizes, int n_in,
                              void* d_out, int out_size, void* d_ws, size_t ws_size,
                              hipStream_t stream) {
    const float* x  = (const float*)d_in[0];
    const int*   ei = (const int*)  d_in[1];
    const float* W0 = (const float*)d_in[2];
    const float* b0 = (const float*)d_in[3];
    const float* W1 = (const float*)d_in[4];
    const float* b1 = (const float*)d_in[5];
    const float* W2 = (const float*)d_in[6];
    const float* b2 = (const float*)d_in[7];

    const int N = in_sizes[0] / HID;
    const int E = in_sizes[1] / 2;
    const int* row = ei;        // sources
    const int* col = ei + E;    // destinations

    const int nb_n = (N + 255) / 256;

    // workspace layout (all 4-byte elems)
    float* hbuf    = (float*)d_ws;                    // [N,128]  (= h', dinv-scaled)
    float* dinv    = hbuf + (size_t)N * HID;          // [N]
    int*   cnt     = (int*)(dinv + N);                // [N]
    int*   row_ptr = cnt + N;                         // [N+1]
    int*   fill    = row_ptr + (N + 1);               // [N]
    int*   bsum    = fill + N;                        // [nb_n]
    int*   csr_src = bsum + nb_n;                     // [E]
    float* out     = (float*)d_out;                   // [N,128]

    const int nb_e    = (E + 255) / 256;
    const int nb_gemm = (N + BR - 1) / BR;
    const int nb_agg  = (N * 64 + 255) / 256;         // 1 wave per node

    // ---- CSR build ----
    hipMemsetAsync(cnt,  0, (size_t)N * sizeof(int), stream);
    hipMemsetAsync(fill, 0, (size_t)N * sizeof(int), stream);
    k_deg_count<<<nb_e, 256, 0, stream>>>(col, cnt, E);
    k_dinv     <<<nb_n, 256, 0, stream>>>(cnt, dinv, N);
    k_scan_block<<<nb_n, 256, 0, stream>>>(cnt, row_ptr, bsum, N);
    k_scan_bsum <<<1, 1024, 0, stream>>>(bsum, nb_n);
    k_scan_add  <<<nb_n, 256, 0, stream>>>(row_ptr, bsum, N, E);
    k_fill      <<<nb_e, 256, 0, stream>>>(row, col, row_ptr, fill, csr_src, E);

    // ---- layer 0 ----
    k_gemm   <<<nb_gemm, 256, 0, stream>>>(x, W0, dinv, hbuf, N, 0);
    k_agg_csr<<<nb_agg, 256, 0, stream>>>(hbuf, csr_src, row_ptr, dinv, b0, out, N);
    // ---- layer 1 ----
    k_gemm   <<<nb_gemm, 256, 0, stream>>>(out, W1, dinv, hbuf, N, 1);
    k_agg_csr<<<nb_agg, 256, 0, stream>>>(hbuf, csr_src, row_ptr, dinv, b1, out, N);
    // ---- layer 2 ----
    k_gemm   <<<nb_gemm, 256, 0, stream>>>(out, W2, dinv, hbuf, N, 2 ? 1 : 1);
    k_agg_csr<<<nb_agg, 256, 0, stream>>>(hbuf, csr_src, row_ptr, dinv, b2, out, N);
}

// Round 4
// 733.225 us; speedup vs baseline: 11.6256x; 1.1623x over previous
//
#include <hip/hip_runtime.h>

#define HID 128
#define BR  64    // GEMM rows per block

// ================= degree / CSR build =================

__global__ void k_deg_count(const int* __restrict__ col, int* __restrict__ cnt, int E) {
    int e = blockIdx.x * 256 + threadIdx.x;
    if (e < E) atomicAdd(&cnt[col[e]], 1);
}

// scan stage 1 + dinv fused: per-256-block exclusive partials + block sums + dinv
__global__ void k_scan_block(const int* __restrict__ cnt, int* __restrict__ excl,
                             int* __restrict__ bsum, float* __restrict__ dinv, int N) {
    __shared__ int s[256];
    int i = blockIdx.x * 256 + threadIdx.x;
    int v = (i < N) ? cnt[i] : 0;
    if (i < N) dinv[i] = 1.0f / sqrtf((float)(v + 1));   // +1 = self-loop
    s[threadIdx.x] = v;
    __syncthreads();
    for (int off = 1; off < 256; off <<= 1) {
        int t = (threadIdx.x >= off) ? s[threadIdx.x - off] : 0;
        __syncthreads();
        s[threadIdx.x] += t;
        __syncthreads();
    }
    if (i < N) excl[i] = s[threadIdx.x] - v;
    if (threadIdx.x == 255) bsum[blockIdx.x] = s[255];
}

__global__ __launch_bounds__(1024) void k_scan_bsum(int* __restrict__ bsum, int nb) {
    __shared__ int s[1024];
    int i = threadIdx.x;
    int v = (i < nb) ? bsum[i] : 0;
    s[i] = v;
    __syncthreads();
    for (int off = 1; off < 1024; off <<= 1) {
        int t = (i >= off) ? s[i - off] : 0;
        __syncthreads();
        s[i] += t;
        __syncthreads();
    }
    if (i < nb) bsum[i] = s[i] - v;
}

__global__ void k_scan_add(int* __restrict__ row_ptr, const int* __restrict__ bsum,
                           int N, int E) {
    int i = blockIdx.x * 256 + threadIdx.x;
    if (i < N) row_ptr[i] += bsum[blockIdx.x];
    if (i == 0) row_ptr[N] = E;
}

__global__ void k_fill(const int* __restrict__ row, const int* __restrict__ col,
                       const int* __restrict__ row_ptr, int* __restrict__ fill,
                       int* __restrict__ csr_src, int E) {
    int e = blockIdx.x * 256 + threadIdx.x;
    if (e < E) {
        int c = col[e];
        int p = row_ptr[c] + atomicAdd(&fill[c], 1);
        csr_src[p] = row[e];
    }
}

// ================= GEMM: H = dinv .* (act(X) @ W) =================
// LDS holds only the X tile (32 KB, swizzled) -> 4-5 blocks/CU.
// W is read straight from global (same lines for every block -> L1/L2 resident).
// 256 threads: thread (rg=t>>4, cg=t&15) owns rows rg*4..+3, cols cg*8..+7.
// Swizzle: element (r,c) lives at Xs[r*128 + (c ^ ((r>>2)<<2))] -> the 16 distinct
// row-addresses of a per-k read land on 8 banks x 2 (2-way = free).

__global__ __launch_bounds__(256, 4) void k_gemm(const float* __restrict__ X,
                                                 const float* __restrict__ W,
                                                 const float* __restrict__ dinv,
                                                 float* __restrict__ H,
                                                 int N, int relu_in) {
    __shared__ float Xs[BR * HID];    // 32 KB
    const int t = threadIdx.x;
    const int row0 = blockIdx.x * BR;

    // stage X tile: 64 rows x 32 float4, ReLU fused, swizzled
    for (int i = t; i < BR * HID / 4; i += 256) {
        int r = i >> 5, cc = i & 31;
        int gr = row0 + r;
        float4 v = make_float4(0.f, 0.f, 0.f, 0.f);
        if (gr < N) {
            v = reinterpret_cast<const float4*>(X + (size_t)gr * HID)[cc];
            if (relu_in) {
                v.x = fmaxf(v.x, 0.f); v.y = fmaxf(v.y, 0.f);
                v.z = fmaxf(v.z, 0.f); v.w = fmaxf(v.w, 0.f);
            }
        }
        int colq = (cc * 4) ^ ((r >> 2) << 2);
        *reinterpret_cast<float4*>(&Xs[r * HID + colq]) = v;
    }
    __syncthreads();

    const int rg = t >> 4;          // 0..15
    const int cg = t & 15;          // 0..15
    const int r0 = rg * 4;
    const int c0 = cg * 8;
    const int swz = rg << 2;        // == ((r>>2)<<2) for rows r0..r0+3

    float acc[4][8];
#pragma unroll
    for (int i = 0; i < 4; ++i)
#pragma unroll
        for (int j = 0; j < 8; ++j) acc[i][j] = 0.f;

#pragma unroll 4
    for (int k = 0; k < HID; ++k) {
        const float4 w0 = *reinterpret_cast<const float4*>(&W[k * HID + c0]);
        const float4 w1 = *reinterpret_cast<const float4*>(&W[k * HID + c0 + 4]);
        const float wv[8] = {w0.x, w0.y, w0.z, w0.w, w1.x, w1.y, w1.z, w1.w};
        const int kk = k ^ swz;
        float xv[4];
#pragma unroll
        for (int i = 0; i < 4; ++i) xv[i] = Xs[(r0 + i) * HID + kk];
#pragma unroll
        for (int i = 0; i < 4; ++i)
#pragma unroll
            for (int j = 0; j < 8; ++j)
                acc[i][j] = fmaf(xv[i], wv[j], acc[i][j]);
    }

#pragma unroll
    for (int i = 0; i < 4; ++i) {
        int gr = row0 + r0 + i;
        if (gr < N) {
            float d = dinv[gr];
            float4 o0 = make_float4(acc[i][0] * d, acc[i][1] * d, acc[i][2] * d, acc[i][3] * d);
            float4 o1 = make_float4(acc[i][4] * d, acc[i][5] * d, acc[i][6] * d, acc[i][7] * d);
            float4* o = reinterpret_cast<float4*>(H + (size_t)gr * HID + c0);
            o[0] = o0;
            o[1] = o1;
        }
    }
}

// ================= aggregation (gather, pre-scaled h', unroll 8) =================
// h' rows already carry dinv[src]; out[i] = dinv[i]*(h'[i] + sum_j h'[src_j]) + b
// One wave per node (node index wave-uniform -> csr_src reads scalarize).

__global__ __launch_bounds__(256) void k_agg_csr(const float* __restrict__ h,
                                                 const int* __restrict__ csr_src,
                                                 const int* __restrict__ row_ptr,
                                                 const float* __restrict__ dinv,
                                                 const float* __restrict__ bias,
                                                 float* __restrict__ out, int N) {
    int node = (blockIdx.x * 256 + threadIdx.x) >> 6;
    if (node >= N) return;
    int lane = threadIdx.x & 63;
    int c = lane * 2;

    const float2 hs = *reinterpret_cast<const float2*>(h + (size_t)node * HID + c);
    float accx = hs.x, accy = hs.y;

    int j = row_ptr[node];
    const int end = row_ptr[node + 1];

    for (; j + 8 <= end; j += 8) {
        int s0 = csr_src[j];
        int s1 = csr_src[j + 1];
        int s2 = csr_src[j + 2];
        int s3 = csr_src[j + 3];
        int s4 = csr_src[j + 4];
        int s5 = csr_src[j + 5];
        int s6 = csr_src[j + 6];
        int s7 = csr_src[j + 7];
        float2 h0 = *reinterpret_cast<const float2*>(h + (size_t)s0 * HID + c);
        float2 h1 = *reinterpret_cast<const float2*>(h + (size_t)s1 * HID + c);
        float2 h2 = *reinterpret_cast<const float2*>(h + (size_t)s2 * HID + c);
        float2 h3 = *reinterpret_cast<const float2*>(h + (size_t)s3 * HID + c);
        float2 h4 = *reinterpret_cast<const float2*>(h + (size_t)s4 * HID + c);
        float2 h5 = *reinterpret_cast<const float2*>(h + (size_t)s5 * HID + c);
        float2 h6 = *reinterpret_cast<const float2*>(h + (size_t)s6 * HID + c);
        float2 h7 = *reinterpret_cast<const float2*>(h + (size_t)s7 * HID + c);
        accx += ((h0.x + h1.x) + (h2.x + h3.x)) + ((h4.x + h5.x) + (h6.x + h7.x));
        accy += ((h0.y + h1.y) + (h2.y + h3.y)) + ((h4.y + h5.y) + (h6.y + h7.y));
    }
    for (; j < end; ++j) {
        int s = csr_src[j];
        float2 hv = *reinterpret_cast<const float2*>(h + (size_t)s * HID + c);
        accx += hv.x;
        accy += hv.y;
    }

    float di = dinv[node];
    float2 o;
    o.x = fmaf(di, accx, bias[c]);
    o.y = fmaf(di, accy, bias[c + 1]);
    *reinterpret_cast<float2*>(out + (size_t)node * HID + c) = o;
}

// ================= launch =================

extern "C" void kernel_launch(void* const* d_in, const int* in_sizes, int n_in,
                              void* d_out, int out_size, void* d_ws, size_t ws_size,
                              hipStream_t stream) {
    const float* x  = (const float*)d_in[0];
    const int*   ei = (const int*)  d_in[1];
    const float* W0 = (const float*)d_in[2];
    const float* b0 = (const float*)d_in[3];
    const float* W1 = (const float*)d_in[4];
    const float* b1 = (const float*)d_in[5];
    const float* W2 = (const float*)d_in[6];
    const float* b2 = (const float*)d_in[7];

    const int N = in_sizes[0] / HID;
    const int E = in_sizes[1] / 2;
    const int* row = ei;        // sources
    const int* col = ei + E;    // destinations

    const int nb_n = (N + 255) / 256;

    // workspace layout (all 4-byte elems)
    float* hbuf    = (float*)d_ws;                    // [N,128]  (= h', dinv-scaled)
    float* dinv    = hbuf + (size_t)N * HID;          // [N]
    int*   cnt     = (int*)(dinv + N);                // [N]
    int*   row_ptr = cnt + N;                         // [N+1]
    int*   fill    = row_ptr + (N + 1);               // [N]
    int*   bsum    = fill + N;                        // [nb_n]
    int*   csr_src = bsum + nb_n;                     // [E]
    float* out     = (float*)d_out;                   // [N,128]

    const int nb_e    = (E + 255) / 256;
    const int nb_gemm = (N + BR - 1) / BR;
    const int nb_agg  = (N * 64 + 255) / 256;         // 1 wave per node

    // ---- CSR build ----
    hipMemsetAsync(cnt,  0, (size_t)N * sizeof(int), stream);
    hipMemsetAsync(fill, 0, (size_t)N * sizeof(int), stream);
    k_deg_count <<<nb_e, 256, 0, stream>>>(col, cnt, E);
    k_scan_block<<<nb_n, 256, 0, stream>>>(cnt, row_ptr, bsum, dinv, N);
    k_scan_bsum <<<1, 1024, 0, stream>>>(bsum, nb_n);
    k_scan_add  <<<nb_n, 256, 0, stream>>>(row_ptr, bsum, N, E);
    k_fill      <<<nb_e, 256, 0, stream>>>(row, col, row_ptr, fill, csr_src, E);

    // ---- layer 0 ----
    k_gemm   <<<nb_gemm, 256, 0, stream>>>(x, W0, dinv, hbuf, N, 0);
    k_agg_csr<<<nb_agg, 256, 0, stream>>>(hbuf, csr_src, row_ptr, dinv, b0, out, N);
    // ---- layer 1 ----
    k_gemm   <<<nb_gemm, 256, 0, stream>>>(out, W1, dinv, hbuf, N, 1);
    k_agg_csr<<<nb_agg, 256, 0, stream>>>(hbuf, csr_src, row_ptr, dinv, b1, out, N);
    // ---- layer 2 ----
    k_gemm   <<<nb_gemm, 256, 0, stream>>>(out, W2, dinv, hbuf, N, 1);
    k_agg_csr<<<nb_agg, 256, 0, stream>>>(hbuf, csr_src, row_ptr, dinv, b2, out, N);
}

// Round 5
// 689.718 us; speedup vs baseline: 12.3589x; 1.0631x over previous
//
#include <hip/hip_runtime.h>

#define HID 128
#define BR  128   // GEMM rows per block

typedef _Float16 f16;
typedef f16 f16x4 __attribute__((ext_vector_type(4)));
typedef f16 f16x8 __attribute__((ext_vector_type(8)));
typedef float f32x4 __attribute__((ext_vector_type(4)));

// ================= degree / CSR build =================

__global__ void k_deg_count(const int* __restrict__ col, int* __restrict__ cnt, int E) {
    int e = blockIdx.x * 256 + threadIdx.x;
    if (e < E) atomicAdd(&cnt[col[e]], 1);
}

__global__ void k_scan_block(const int* __restrict__ cnt, int* __restrict__ excl,
                             int* __restrict__ bsum, float* __restrict__ dinv, int N) {
    __shared__ int s[256];
    int i = blockIdx.x * 256 + threadIdx.x;
    int v = (i < N) ? cnt[i] : 0;
    if (i < N) dinv[i] = 1.0f / sqrtf((float)(v + 1));   // +1 = self-loop
    s[threadIdx.x] = v;
    __syncthreads();
    for (int off = 1; off < 256; off <<= 1) {
        int t = (threadIdx.x >= off) ? s[threadIdx.x - off] : 0;
        __syncthreads();
        s[threadIdx.x] += t;
        __syncthreads();
    }
    if (i < N) excl[i] = s[threadIdx.x] - v;
    if (threadIdx.x == 255) bsum[blockIdx.x] = s[255];
}

__global__ __launch_bounds__(1024) void k_scan_bsum(int* __restrict__ bsum, int nb) {
    __shared__ int s[1024];
    int i = threadIdx.x;
    int v = (i < nb) ? bsum[i] : 0;
    s[i] = v;
    __syncthreads();
    for (int off = 1; off < 1024; off <<= 1) {
        int t = (i >= off) ? s[i - off] : 0;
        __syncthreads();
        s[i] += t;
        __syncthreads();
    }
    if (i < nb) bsum[i] = s[i] - v;
}

__global__ void k_scan_add(int* __restrict__ row_ptr, const int* __restrict__ bsum,
                           int N, int E) {
    int i = blockIdx.x * 256 + threadIdx.x;
    if (i < N) row_ptr[i] += bsum[blockIdx.x];
    if (i == 0) row_ptr[N] = E;
}

__global__ void k_fill(const int* __restrict__ row, const int* __restrict__ col,
                       const int* __restrict__ row_ptr, int* __restrict__ fill,
                       int* __restrict__ csr_src, int E) {
    int e = blockIdx.x * 256 + threadIdx.x;
    if (e < E) {
        int c = col[e];
        int p = row_ptr[c] + atomicAdd(&fill[c], 1);
        csr_src[p] = row[e];
    }
}

// ================= W prep: transpose + f16 hi/lo split =================
// In: W [k][n] f32 row-major. Out image (matches GEMM's LDS layout exactly):
//   hi at [0,16384), lo at [16384,32768); element (k,n) -> n*128 + (((k>>3)^(n&7))*8) + (k&7)

__global__ void k_wprep(const float* __restrict__ W, f16* __restrict__ out) {
    int i = blockIdx.x * 256 + threadIdx.x;   // 4096 float4s
    if (i >= 4096) return;
    int k = i >> 5, n0 = (i & 31) * 4;
    float4 v = reinterpret_cast<const float4*>(W)[i];
    float vv[4] = {v.x, v.y, v.z, v.w};
#pragma unroll
    for (int e = 0; e < 4; ++e) {
        int n = n0 + e;
        int idx = n * 128 + (((k >> 3) ^ (n & 7)) * 8) + (k & 7);
        f16 h = (f16)vv[e];
        out[idx] = h;
        out[16384 + idx] = (f16)(vv[e] - (float)h);
    }
}

// ================= GEMM: H = dinv .* (act(X) @ W)  via split-f16 MFMA =================
// x*w = xh*wh + xh*wl + xl*wh (+ O(2^-22) dropped). 512 thr = 8 waves; block tile 128x128.
// Wave w owns rows w*16..+15, all 128 cols: 8 cb x 4 ks x 3 = 96 mfma_f32_16x16x32_f16.
// LDS: Xs hi/lo 64 KB + Ws hi/lo 64 KB = 128 KB (1 block/CU, 2 waves/SIMD).
// 16B-chunk XOR swizzle keeps all ds_read_b128 <=2-way (free).

__global__ __launch_bounds__(512, 1) void k_gemm(const float* __restrict__ X,
                                                 const f16* __restrict__ Wt,
                                                 const float* __restrict__ dinv,
                                                 float* __restrict__ H,
                                                 int N, int relu_in) {
    __shared__ f16 Ws[2 * 16384];
    __shared__ f16 Xs[2 * 16384];
    const int t = threadIdx.x;
    const int row0 = blockIdx.x * BR;

    // stage W image: straight 64 KB copy (4096 float4)
    for (int i = t; i < 4096; i += 512)
        reinterpret_cast<float4*>(Ws)[i] = reinterpret_cast<const float4*>(Wt)[i];

    // stage X tile: 128 rows x 32 float4; ReLU + hi/lo split + swizzled write
    for (int i = t; i < 4096; i += 512) {
        int r = i >> 5, q = i & 31;
        int gr = row0 + r;
        float4 v = make_float4(0.f, 0.f, 0.f, 0.f);
        if (gr < N) {
            v = reinterpret_cast<const float4*>(X + (size_t)gr * HID)[q];
            if (relu_in) {
                v.x = fmaxf(v.x, 0.f); v.y = fmaxf(v.y, 0.f);
                v.z = fmaxf(v.z, 0.f); v.w = fmaxf(v.w, 0.f);
            }
        }
        f16 h0 = (f16)v.x, h1 = (f16)v.y, h2 = (f16)v.z, h3 = (f16)v.w;
        f16 l0 = (f16)(v.x - (float)h0), l1 = (f16)(v.y - (float)h1);
        f16 l2 = (f16)(v.z - (float)h2), l3 = (f16)(v.w - (float)h3);
        int base = r * 128 + (((q >> 1) ^ (r & 7)) * 8) + (q & 1) * 4;
        *reinterpret_cast<f16x4*>(&Xs[base])         = (f16x4){h0, h1, h2, h3};
        *reinterpret_cast<f16x4*>(&Xs[16384 + base]) = (f16x4){l0, l1, l2, l3};
    }
    __syncthreads();

    const int w  = t >> 6;
    const int l  = t & 63;
    const int lg = l >> 4;
    const int li = l & 15;

    // A fragments: row = w*16 + li, k-chunk = ks*4 + lg
    const int arow = w * 16 + li;
    f16x8 Ah[4], Al[4];
#pragma unroll
    for (int ks = 0; ks < 4; ++ks) {
        int idx = arow * 128 + (((ks * 4 + lg) ^ (arow & 7)) * 8);
        Ah[ks] = *reinterpret_cast<const f16x8*>(&Xs[idx]);
        Al[ks] = *reinterpret_cast<const f16x8*>(&Xs[16384 + idx]);
    }

    f32x4 acc[8];
#pragma unroll
    for (int cb = 0; cb < 8; ++cb) acc[cb] = (f32x4){0.f, 0.f, 0.f, 0.f};

#pragma unroll
    for (int cb = 0; cb < 8; ++cb) {
        const int ncol = cb * 16 + li;
#pragma unroll
        for (int ks = 0; ks < 4; ++ks) {
            int idx = ncol * 128 + (((ks * 4 + lg) ^ (ncol & 7)) * 8);
            f16x8 Bh = *reinterpret_cast<const f16x8*>(&Ws[idx]);
            f16x8 Bl = *reinterpret_cast<const f16x8*>(&Ws[16384 + idx]);
            acc[cb] = __builtin_amdgcn_mfma_f32_16x16x32_f16(Ah[ks], Bh, acc[cb], 0, 0, 0);
            acc[cb] = __builtin_amdgcn_mfma_f32_16x16x32_f16(Ah[ks], Bl, acc[cb], 0, 0, 0);
            acc[cb] = __builtin_amdgcn_mfma_f32_16x16x32_f16(Al[ks], Bh, acc[cb], 0, 0, 0);
        }
    }

    // epilogue: D row = (lane>>4)*4 + reg, col = lane&15 (m89 layout); scale by dinv
    float d[4];
    int grow[4];
#pragma unroll
    for (int r = 0; r < 4; ++r) {
        grow[r] = row0 + w * 16 + lg * 4 + r;
        d[r] = (grow[r] < N) ? dinv[grow[r]] : 0.f;
    }
#pragma unroll
    for (int cb = 0; cb < 8; ++cb) {
#pragma unroll
        for (int r = 0; r < 4; ++r) {
            if (grow[r] < N)
                H[(size_t)grow[r] * HID + cb * 16 + li] = acc[cb][r] * d[r];
        }
    }
}

// ================= aggregation (gather, pre-scaled h', unroll 8) =================

__global__ __launch_bounds__(256) void k_agg_csr(const float* __restrict__ h,
                                                 const int* __restrict__ csr_src,
                                                 const int* __restrict__ row_ptr,
                                                 const float* __restrict__ dinv,
                                                 const float* __restrict__ bias,
                                                 float* __restrict__ out, int N) {
    int node = (blockIdx.x * 256 + threadIdx.x) >> 6;
    if (node >= N) return;
    int lane = threadIdx.x & 63;
    int c = lane * 2;

    const float2 hs = *reinterpret_cast<const float2*>(h + (size_t)node * HID + c);
    float accx = hs.x, accy = hs.y;

    int j = row_ptr[node];
    const int end = row_ptr[node + 1];

    for (; j + 8 <= end; j += 8) {
        int s0 = csr_src[j];
        int s1 = csr_src[j + 1];
        int s2 = csr_src[j + 2];
        int s3 = csr_src[j + 3];
        int s4 = csr_src[j + 4];
        int s5 = csr_src[j + 5];
        int s6 = csr_src[j + 6];
        int s7 = csr_src[j + 7];
        float2 h0 = *reinterpret_cast<const float2*>(h + (size_t)s0 * HID + c);
        float2 h1 = *reinterpret_cast<const float2*>(h + (size_t)s1 * HID + c);
        float2 h2 = *reinterpret_cast<const float2*>(h + (size_t)s2 * HID + c);
        float2 h3 = *reinterpret_cast<const float2*>(h + (size_t)s3 * HID + c);
        float2 h4 = *reinterpret_cast<const float2*>(h + (size_t)s4 * HID + c);
        float2 h5 = *reinterpret_cast<const float2*>(h + (size_t)s5 * HID + c);
        float2 h6 = *reinterpret_cast<const float2*>(h + (size_t)s6 * HID + c);
        float2 h7 = *reinterpret_cast<const float2*>(h + (size_t)s7 * HID + c);
        accx += ((h0.x + h1.x) + (h2.x + h3.x)) + ((h4.x + h5.x) + (h6.x + h7.x));
        accy += ((h0.y + h1.y) + (h2.y + h3.y)) + ((h4.y + h5.y) + (h6.y + h7.y));
    }
    for (; j < end; ++j) {
        int s = csr_src[j];
        float2 hv = *reinterpret_cast<const float2*>(h + (size_t)s * HID + c);
        accx += hv.x;
        accy += hv.y;
    }

    float di = dinv[node];
    float2 o;
    o.x = fmaf(di, accx, bias[c]);
    o.y = fmaf(di, accy, bias[c + 1]);
    *reinterpret_cast<float2*>(out + (size_t)node * HID + c) = o;
}

// ================= launch =================

extern "C" void kernel_launch(void* const* d_in, const int* in_sizes, int n_in,
                              void* d_out, int out_size, void* d_ws, size_t ws_size,
                              hipStream_t stream) {
    const float* x  = (const float*)d_in[0];
    const int*   ei = (const int*)  d_in[1];
    const float* W0 = (const float*)d_in[2];
    const float* b0 = (const float*)d_in[3];
    const float* W1 = (const float*)d_in[4];
    const float* b1 = (const float*)d_in[5];
    const float* W2 = (const float*)d_in[6];
    const float* b2 = (const float*)d_in[7];

    const int N = in_sizes[0] / HID;
    const int E = in_sizes[1] / 2;
    const int* row = ei;        // sources
    const int* col = ei + E;    // destinations

    const int nb_n = (N + 255) / 256;

    // workspace layout (4-byte elems unless noted)
    float* hbuf    = (float*)d_ws;                    // [N,128]  (= h', dinv-scaled)
    float* dinv    = hbuf + (size_t)N * HID;          // [N]
    int*   cnt     = (int*)(dinv + N);                // [N]
    int*   row_ptr = cnt + N;                         // [N+1]
    int*   fill    = row_ptr + (N + 1);               // [N]
    int*   bsum    = fill + N;                        // [nb_n]
    int*   csr_src = bsum + nb_n;                     // [E]
    f16*   wt0     = (f16*)(csr_src + E);             // [32768] f16 each
    f16*   wt1     = wt0 + 32768;
    f16*   wt2     = wt1 + 32768;
    float* out     = (float*)d_out;                   // [N,128]

    const int nb_e    = (E + 255) / 256;
    const int nb_gemm = (N + BR - 1) / BR;
    const int nb_agg  = (N * 64 + 255) / 256;         // 1 wave per node

    // ---- CSR build + W prep ----
    hipMemsetAsync(cnt,  0, (size_t)N * sizeof(int), stream);
    hipMemsetAsync(fill, 0, (size_t)N * sizeof(int), stream);
    k_wprep<<<16, 256, 0, stream>>>(W0, wt0);
    k_wprep<<<16, 256, 0, stream>>>(W1, wt1);
    k_wprep<<<16, 256, 0, stream>>>(W2, wt2);
    k_deg_count <<<nb_e, 256, 0, stream>>>(col, cnt, E);
    k_scan_block<<<nb_n, 256, 0, stream>>>(cnt, row_ptr, bsum, dinv, N);
    k_scan_bsum <<<1, 1024, 0, stream>>>(bsum, nb_n);
    k_scan_add  <<<nb_n, 256, 0, stream>>>(row_ptr, bsum, N, E);
    k_fill      <<<nb_e, 256, 0, stream>>>(row, col, row_ptr, fill, csr_src, E);

    // ---- layer 0 ----
    k_gemm   <<<nb_gemm, 512, 0, stream>>>(x, wt0, dinv, hbuf, N, 0);
    k_agg_csr<<<nb_agg, 256, 0, stream>>>(hbuf, csr_src, row_ptr, dinv, b0, out, N);
    // ---- layer 1 ----
    k_gemm   <<<nb_gemm, 512, 0, stream>>>(out, wt1, dinv, hbuf, N, 1);
    k_agg_csr<<<nb_agg, 256, 0, stream>>>(hbuf, csr_src, row_ptr, dinv, b1, out, N);
    // ---- layer 2 ----
    k_gemm   <<<nb_gemm, 512, 0, stream>>>(out, wt2, dinv, hbuf, N, 1);
    k_agg_csr<<<nb_agg, 256, 0, stream>>>(hbuf, csr_src, row_ptr, dinv, b2, out, N);
}

// Round 6
// 652.079 us; speedup vs baseline: 13.0723x; 1.0577x over previous
//
#include <hip/hip_runtime.h>

#define HID 128
#define BR  128   // GEMM rows per block

typedef _Float16 f16;
typedef f16 f16x4 __attribute__((ext_vector_type(4)));
typedef f16 f16x8 __attribute__((ext_vector_type(8)));
typedef float f32x4 __attribute__((ext_vector_type(4)));

// ================= degree / CSR build =================

__global__ void k_deg_count(const int* __restrict__ col, int* __restrict__ cnt, int E) {
    int e = blockIdx.x * 256 + threadIdx.x;
    if (e < E) atomicAdd(&cnt[col[e]], 1);
}

__global__ void k_scan_block(const int* __restrict__ cnt, int* __restrict__ excl,
                             int* __restrict__ bsum, float* __restrict__ dinv, int N) {
    __shared__ int s[256];
    int i = blockIdx.x * 256 + threadIdx.x;
    int v = (i < N) ? cnt[i] : 0;
    if (i < N) dinv[i] = 1.0f / sqrtf((float)(v + 1));   // +1 = self-loop
    s[threadIdx.x] = v;
    __syncthreads();
    for (int off = 1; off < 256; off <<= 1) {
        int t = (threadIdx.x >= off) ? s[threadIdx.x - off] : 0;
        __syncthreads();
        s[threadIdx.x] += t;
        __syncthreads();
    }
    if (i < N) excl[i] = s[threadIdx.x] - v;
    if (threadIdx.x == 255) bsum[blockIdx.x] = s[255];
}

__global__ __launch_bounds__(1024) void k_scan_bsum(int* __restrict__ bsum, int nb) {
    __shared__ int s[1024];
    int i = threadIdx.x;
    int v = (i < nb) ? bsum[i] : 0;
    s[i] = v;
    __syncthreads();
    for (int off = 1; off < 1024; off <<= 1) {
        int t = (i >= off) ? s[i - off] : 0;
        __syncthreads();
        s[i] += t;
        __syncthreads();
    }
    if (i < nb) bsum[i] = s[i] - v;
}

// adds block offsets; also emits the fill-cursor copy so k_fill needs no memset/extra read
__global__ void k_scan_add(int* __restrict__ row_ptr, const int* __restrict__ bsum,
                           int* __restrict__ fill, int N, int E) {
    int i = blockIdx.x * 256 + threadIdx.x;
    if (i < N) {
        int v = row_ptr[i] + bsum[blockIdx.x];
        row_ptr[i] = v;
        fill[i] = v;
    }
    if (i == 0) row_ptr[N] = E;
}

__global__ void k_fill(const int* __restrict__ row, const int* __restrict__ col,
                       int* __restrict__ fill, int* __restrict__ csr_src, int E) {
    int e = blockIdx.x * 256 + threadIdx.x;
    if (e < E) {
        int p = atomicAdd(&fill[col[e]], 1);
        csr_src[p] = row[e];
    }
}

// ================= W prep: transpose + f16 hi/lo split =================
// In: W [k][n] f32. Out image: element (k,n) -> (k>>3)*1024 + n*8 + (k&7);
// hi at [0,16384), lo at [16384,32768). B-frag (kc,n) is 8 contiguous f16 =
// one dwordx4; lanes (consecutive n) read consecutive 16B -> coalesced.

__global__ void k_wprep(const float* __restrict__ W, f16* __restrict__ out) {
    int i = blockIdx.x * 256 + threadIdx.x;   // 4096 float4s
    if (i >= 4096) return;
    int k = i >> 5, n0 = (i & 31) * 4;
    float4 v = reinterpret_cast<const float4*>(W)[i];
    float vv[4] = {v.x, v.y, v.z, v.w};
#pragma unroll
    for (int e = 0; e < 4; ++e) {
        int n = n0 + e;
        int idx = (k >> 3) * 1024 + n * 8 + (k & 7);
        f16 h = (f16)vv[e];
        out[idx] = h;
        out[16384 + idx] = (f16)(vv[e] - (float)h);
    }
}

// ================= GEMM: H = dinv .* (act(X) @ W)  via split-f16 MFMA =================
// x*w = xh*wh + xh*wl + xl*wh (dropped term ~2^-22). 512 thr = 8 waves (2 rg x 4 cg);
// wave owns 64 rows x 32 cols. LDS: X hi/lo only (64 KB) -> 2 blocks/CU.
// B fragments live in VGPRs, loaded from global (L1/L2-hot) BEFORE X staging.
// Per wave: 32 ds_read_b128 + 96 mfma_16x16x32_f16.

__global__ __launch_bounds__(512, 4) void k_gemm(const float* __restrict__ X,
                                                 const f16* __restrict__ Wt,
                                                 const float* __restrict__ dinv,
                                                 float* __restrict__ H,
                                                 int N, int relu_in) {
    __shared__ f16 Xs[2 * 16384];   // 64 KB: hi [0,16384), lo [16384,)
    const int t = threadIdx.x;
    const int row0 = blockIdx.x * BR;

    const int w  = t >> 6;
    const int l  = t & 63;
    const int lg = l >> 4;
    const int li = l & 15;
    const int rg = w >> 2;          // 0..1
    const int cg = w & 3;           // 0..3

    // ---- B fragments: issue global loads first (latency hides under X staging) ----
    f16x8 Bh[2][4], Bl[2][4];
#pragma unroll
    for (int cb = 0; cb < 2; ++cb) {
        const int ncol = cg * 32 + cb * 16 + li;
#pragma unroll
        for (int ks = 0; ks < 4; ++ks) {
            const int idx = (ks * 4 + lg) * 1024 + ncol * 8;
            Bh[cb][ks] = *reinterpret_cast<const f16x8*>(&Wt[idx]);
            Bl[cb][ks] = *reinterpret_cast<const f16x8*>(&Wt[16384 + idx]);
        }
    }

    // ---- stage X tile: 128 rows x 32 float4; ReLU + hi/lo split + 16B-chunk swizzle ----
    for (int i = t; i < 4096; i += 512) {
        int r = i >> 5, q = i & 31;
        int gr = row0 + r;
        float4 v = make_float4(0.f, 0.f, 0.f, 0.f);
        if (gr < N) {
            v = reinterpret_cast<const float4*>(X + (size_t)gr * HID)[q];
            if (relu_in) {
                v.x = fmaxf(v.x, 0.f); v.y = fmaxf(v.y, 0.f);
                v.z = fmaxf(v.z, 0.f); v.w = fmaxf(v.w, 0.f);
            }
        }
        f16 h0 = (f16)v.x, h1 = (f16)v.y, h2 = (f16)v.z, h3 = (f16)v.w;
        f16 l0 = (f16)(v.x - (float)h0), l1 = (f16)(v.y - (float)h1);
        f16 l2 = (f16)(v.z - (float)h2), l3 = (f16)(v.w - (float)h3);
        int base = r * 128 + (((q >> 1) ^ (r & 7)) * 8) + (q & 1) * 4;
        *reinterpret_cast<f16x4*>(&Xs[base])         = (f16x4){h0, h1, h2, h3};
        *reinterpret_cast<f16x4*>(&Xs[16384 + base]) = (f16x4){l0, l1, l2, l3};
    }
    __syncthreads();

    f32x4 acc[4][2];
#pragma unroll
    for (int rb = 0; rb < 4; ++rb)
#pragma unroll
        for (int cb = 0; cb < 2; ++cb) acc[rb][cb] = (f32x4){0.f, 0.f, 0.f, 0.f};

#pragma unroll
    for (int rb = 0; rb < 4; ++rb) {
        const int arow = rg * 64 + rb * 16 + li;
#pragma unroll
        for (int ks = 0; ks < 4; ++ks) {
            const int idx = arow * 128 + (((ks * 4 + lg) ^ (arow & 7)) * 8);
            f16x8 Ah = *reinterpret_cast<const f16x8*>(&Xs[idx]);
            f16x8 Al = *reinterpret_cast<const f16x8*>(&Xs[16384 + idx]);
#pragma unroll
            for (int cb = 0; cb < 2; ++cb) {
                acc[rb][cb] = __builtin_amdgcn_mfma_f32_16x16x32_f16(Ah, Bh[cb][ks], acc[rb][cb], 0, 0, 0);
                acc[rb][cb] = __builtin_amdgcn_mfma_f32_16x16x32_f16(Ah, Bl[cb][ks], acc[rb][cb], 0, 0, 0);
                acc[rb][cb] = __builtin_amdgcn_mfma_f32_16x16x32_f16(Al, Bh[cb][ks], acc[rb][cb], 0, 0, 0);
            }
        }
    }

    // ---- epilogue: D col = lane&15, row = (lane>>4)*4 + reg (m89); scale by dinv ----
#pragma unroll
    for (int rb = 0; rb < 4; ++rb) {
#pragma unroll
        for (int r = 0; r < 4; ++r) {
            const int grow = row0 + rg * 64 + rb * 16 + lg * 4 + r;
            if (grow < N) {
                const float d = dinv[grow];
#pragma unroll
                for (int cb = 0; cb < 2; ++cb)
                    H[(size_t)grow * HID + cg * 32 + cb * 16 + li] = acc[rb][cb][r] * d;
            }
        }
    }
}

// ================= aggregation (gather, pre-scaled h', unroll 8) =================

__global__ __launch_bounds__(256) void k_agg_csr(const float* __restrict__ h,
                                                 const int* __restrict__ csr_src,
                                                 const int* __restrict__ row_ptr,
                                                 const float* __restrict__ dinv,
                                                 const float* __restrict__ bias,
                                                 float* __restrict__ out, int N) {
    int node = (blockIdx.x * 256 + threadIdx.x) >> 6;
    if (node >= N) return;
    int lane = threadIdx.x & 63;
    int c = lane * 2;

    const float2 hs = *reinterpret_cast<const float2*>(h + (size_t)node * HID + c);
    float accx = hs.x, accy = hs.y;

    int j = row_ptr[node];
    const int end = row_ptr[node + 1];

    for (; j + 8 <= end; j += 8) {
        int s0 = csr_src[j];
        int s1 = csr_src[j + 1];
        int s2 = csr_src[j + 2];
        int s3 = csr_src[j + 3];
        int s4 = csr_src[j + 4];
        int s5 = csr_src[j + 5];
        int s6 = csr_src[j + 6];
        int s7 = csr_src[j + 7];
        float2 h0 = *reinterpret_cast<const float2*>(h + (size_t)s0 * HID + c);
        float2 h1 = *reinterpret_cast<const float2*>(h + (size_t)s1 * HID + c);
        float2 h2 = *reinterpret_cast<const float2*>(h + (size_t)s2 * HID + c);
        float2 h3 = *reinterpret_cast<const float2*>(h + (size_t)s3 * HID + c);
        float2 h4 = *reinterpret_cast<const float2*>(h + (size_t)s4 * HID + c);
        float2 h5 = *reinterpret_cast<const float2*>(h + (size_t)s5 * HID + c);
        float2 h6 = *reinterpret_cast<const float2*>(h + (size_t)s6 * HID + c);
        float2 h7 = *reinterpret_cast<const float2*>(h + (size_t)s7 * HID + c);
        accx += ((h0.x + h1.x) + (h2.x + h3.x)) + ((h4.x + h5.x) + (h6.x + h7.x));
        accy += ((h0.y + h1.y) + (h2.y + h3.y)) + ((h4.y + h5.y) + (h6.y + h7.y));
    }
    for (; j < end; ++j) {
        int s = csr_src[j];
        float2 hv = *reinterpret_cast<const float2*>(h + (size_t)s * HID + c);
        accx += hv.x;
        accy += hv.y;
    }

    float di = dinv[node];
    float2 o;
    o.x = fmaf(di, accx, bias[c]);
    o.y = fmaf(di, accy, bias[c + 1]);
    *reinterpret_cast<float2*>(out + (size_t)node * HID + c) = o;
}

// ================= launch =================

extern "C" void kernel_launch(void* const* d_in, const int* in_sizes, int n_in,
                              void* d_out, int out_size, void* d_ws, size_t ws_size,
                              hipStream_t stream) {
    const float* x  = (const float*)d_in[0];
    const int*   ei = (const int*)  d_in[1];
    const float* W0 = (const float*)d_in[2];
    const float* b0 = (const float*)d_in[3];
    const float* W1 = (const float*)d_in[4];
    const float* b1 = (const float*)d_in[5];
    const float* W2 = (const float*)d_in[6];
    const float* b2 = (const float*)d_in[7];

    const int N = in_sizes[0] / HID;
    const int E = in_sizes[1] / 2;
    const int* row = ei;        // sources
    const int* col = ei + E;    // destinations

    const int nb_n = (N + 255) / 256;

    // workspace layout (4-byte elems unless noted)
    float* hbuf    = (float*)d_ws;                    // [N,128]  (= h', dinv-scaled)
    float* dinv    = hbuf + (size_t)N * HID;          // [N]
    int*   cnt     = (int*)(dinv + N);                // [N]
    int*   row_ptr = cnt + N;                         // [N+1]
    int*   fill    = row_ptr + (N + 1);               // [N]
    int*   bsum    = fill + N;                        // [nb_n]
    int*   csr_src = bsum + nb_n;                     // [E]
    f16*   wt0     = (f16*)(csr_src + E);             // [32768] f16 each
    f16*   wt1     = wt0 + 32768;
    f16*   wt2     = wt1 + 32768;
    float* out     = (float*)d_out;                   // [N,128]

    const int nb_e    = (E + 255) / 256;
    const int nb_gemm = (N + BR - 1) / BR;
    const int nb_agg  = (N * 64 + 255) / 256;         // 1 wave per node

    // ---- CSR build + W prep ----
    hipMemsetAsync(cnt, 0, (size_t)N * sizeof(int), stream);
    k_wprep<<<16, 256, 0, stream>>>(W0, wt0);
    k_wprep<<<16, 256, 0, stream>>>(W1, wt1);
    k_wprep<<<16, 256, 0, stream>>>(W2, wt2);
    k_deg_count <<<nb_e, 256, 0, stream>>>(col, cnt, E);
    k_scan_block<<<nb_n, 256, 0, stream>>>(cnt, row_ptr, bsum, dinv, N);
    k_scan_bsum <<<1, 1024, 0, stream>>>(bsum, nb_n);
    k_scan_add  <<<nb_n, 256, 0, stream>>>(row_ptr, bsum, fill, N, E);
    k_fill      <<<nb_e, 256, 0, stream>>>(row, col, fill, csr_src, E);

    // ---- layer 0 ----
    k_gemm   <<<nb_gemm, 512, 0, stream>>>(x, wt0, dinv, hbuf, N, 0);
    k_agg_csr<<<nb_agg, 256, 0, stream>>>(hbuf, csr_src, row_ptr, dinv, b0, out, N);
    // ---- layer 1 ----
    k_gemm   <<<nb_gemm, 512, 0, stream>>>(out, wt1, dinv, hbuf, N, 1);
    k_agg_csr<<<nb_agg, 256, 0, stream>>>(hbuf, csr_src, row_ptr, dinv, b1, out, N);
    // ---- layer 2 ----
    k_gemm   <<<nb_gemm, 512, 0, stream>>>(out, wt2, dinv, hbuf, N, 1);
    k_agg_csr<<<nb_agg, 256, 0, stream>>>(hbuf, csr_src, row_ptr, dinv, b2, out, N);
}

// Round 7
// 471.181 us; speedup vs baseline: 18.0911x; 1.3839x over previous
//
#include <hip/hip_runtime.h>

#define HID 128
#define BR  128        // GEMM rows per block
#define FILL_CHUNK 2048

typedef _Float16 f16;
typedef f16 f16x2 __attribute__((ext_vector_type(2)));
typedef f16 f16x4 __attribute__((ext_vector_type(4)));
typedef f16 f16x8 __attribute__((ext_vector_type(8)));
typedef float f32x4 __attribute__((ext_vector_type(4)));

static __device__ __forceinline__ float2 h2f(unsigned int u) {
    f16x2 v;
    __builtin_memcpy(&v, &u, 4);
    return make_float2((float)v[0], (float)v[1]);
}

// ================= degree / CSR build =================

__global__ void k_deg_count(const int* __restrict__ col, int* __restrict__ cnt, int E) {
    int e = blockIdx.x * 256 + threadIdx.x;
    if (e < E) atomicAdd(&cnt[col[e]], 1);
}

__global__ void k_scan_block(const int* __restrict__ cnt, int* __restrict__ excl,
                             int* __restrict__ bsum, float* __restrict__ dinv, int N) {
    __shared__ int s[256];
    int i = blockIdx.x * 256 + threadIdx.x;
    int v = (i < N) ? cnt[i] : 0;
    if (i < N) dinv[i] = 1.0f / sqrtf((float)(v + 1));   // +1 = self-loop
    s[threadIdx.x] = v;
    __syncthreads();
    for (int off = 1; off < 256; off <<= 1) {
        int t = (threadIdx.x >= off) ? s[threadIdx.x - off] : 0;
        __syncthreads();
        s[threadIdx.x] += t;
        __syncthreads();
    }
    if (i < N) excl[i] = s[threadIdx.x] - v;
    if (threadIdx.x == 255) bsum[blockIdx.x] = s[255];
}

__global__ __launch_bounds__(1024) void k_scan_bsum(int* __restrict__ bsum, int nb) {
    __shared__ int s[1024];
    int i = threadIdx.x;
    int v = (i < nb) ? bsum[i] : 0;
    s[i] = v;
    __syncthreads();
    for (int off = 1; off < 1024; off <<= 1) {
        int t = (i >= off) ? s[i - off] : 0;
        __syncthreads();
        s[i] += t;
        __syncthreads();
    }
    if (i < nb) bsum[i] = s[i] - v;
}

__global__ void k_scan_add(int* __restrict__ row_ptr, const int* __restrict__ bsum,
                           int* __restrict__ fill, int N, int E) {
    int i = blockIdx.x * 256 + threadIdx.x;
    if (i < N) {
        int v = row_ptr[i] + bsum[blockIdx.x];
        row_ptr[i] = v;
        fill[i] = v;
    }
    if (i == 0) row_ptr[N] = E;
}

// XCD-range-filtered scatter: block b -> edge chunk (b>>3), col-range (b&7).
// Each XCD's csr_src writes confine to an ~800 KB window -> lines fill in L2.
__global__ void k_fill(const int* __restrict__ row, const int* __restrict__ col,
                       int* __restrict__ fill, int* __restrict__ csr_src, int E, int N) {
    const int xcd = blockIdx.x & 7;
    const int chunk = blockIdx.x >> 3;
    const int per = (N + 7) >> 3;
    const int lo = xcd * per;
    const int hi = min(N, lo + per);
    const int eend = min(E, (chunk + 1) * FILL_CHUNK);
    for (int e = chunk * FILL_CHUNK + threadIdx.x; e < eend; e += 256) {
        int c = col[e];
        if (c >= lo && c < hi) {
            int p = atomicAdd(&fill[c], 1);
            csr_src[p] = row[e];
        }
    }
}

// ================= W prep: transpose + f16 hi/lo split =================
// element (k,n) -> (k>>3)*1024 + n*8 + (k&7); hi [0,16384), lo [16384,32768)

__global__ void k_wprep(const float* __restrict__ W, f16* __restrict__ out) {
    int i = blockIdx.x * 256 + threadIdx.x;   // 4096 float4s
    if (i >= 4096) return;
    int k = i >> 5, n0 = (i & 31) * 4;
    float4 v = reinterpret_cast<const float4*>(W)[i];
    float vv[4] = {v.x, v.y, v.z, v.w};
#pragma unroll
    for (int e = 0; e < 4; ++e) {
        int n = n0 + e;
        int idx = (k >> 3) * 1024 + n * 8 + (k & 7);
        f16 h = (f16)vv[e];
        out[idx] = h;
        out[16384 + idx] = (f16)(vv[e] - (float)h);
    }
}

// ================= GEMM: H16 = f16( dinv .* (act(X) @ W) )  via split-f16 MFMA =================

__global__ __launch_bounds__(512, 4) void k_gemm(const float* __restrict__ X,
                                                 const f16* __restrict__ Wt,
                                                 const float* __restrict__ dinv,
                                                 f16* __restrict__ H,
                                                 int N, int relu_in) {
    __shared__ f16 Xs[2 * 16384];   // 64 KB: hi [0,16384), lo [16384,)
    const int t = threadIdx.x;
    const int row0 = blockIdx.x * BR;

    const int w  = t >> 6;
    const int l  = t & 63;
    const int lg = l >> 4;
    const int li = l & 15;
    const int rg = w >> 2;          // 0..1
    const int cg = w & 3;           // 0..3

    // B fragments from global, issued before X staging (latency hidden)
    f16x8 Bh[2][4], Bl[2][4];
#pragma unroll
    for (int cb = 0; cb < 2; ++cb) {
        const int ncol = cg * 32 + cb * 16 + li;
#pragma unroll
        for (int ks = 0; ks < 4; ++ks) {
            const int idx = (ks * 4 + lg) * 1024 + ncol * 8;
            Bh[cb][ks] = *reinterpret_cast<const f16x8*>(&Wt[idx]);
            Bl[cb][ks] = *reinterpret_cast<const f16x8*>(&Wt[16384 + idx]);
        }
    }

    // stage X tile: ReLU + hi/lo split + 16B-chunk swizzle
    for (int i = t; i < 4096; i += 512) {
        int r = i >> 5, q = i & 31;
        int gr = row0 + r;
        float4 v = make_float4(0.f, 0.f, 0.f, 0.f);
        if (gr < N) {
            v = reinterpret_cast<const float4*>(X + (size_t)gr * HID)[q];
            if (relu_in) {
                v.x = fmaxf(v.x, 0.f); v.y = fmaxf(v.y, 0.f);
                v.z = fmaxf(v.z, 0.f); v.w = fmaxf(v.w, 0.f);
            }
        }
        f16 h0 = (f16)v.x, h1 = (f16)v.y, h2 = (f16)v.z, h3 = (f16)v.w;
        f16 l0 = (f16)(v.x - (float)h0), l1 = (f16)(v.y - (float)h1);
        f16 l2 = (f16)(v.z - (float)h2), l3 = (f16)(v.w - (float)h3);
        int base = r * 128 + (((q >> 1) ^ (r & 7)) * 8) + (q & 1) * 4;
        *reinterpret_cast<f16x4*>(&Xs[base])         = (f16x4){h0, h1, h2, h3};
        *reinterpret_cast<f16x4*>(&Xs[16384 + base]) = (f16x4){l0, l1, l2, l3};
    }
    __syncthreads();

    f32x4 acc[4][2];
#pragma unroll
    for (int rb = 0; rb < 4; ++rb)
#pragma unroll
        for (int cb = 0; cb < 2; ++cb) acc[rb][cb] = (f32x4){0.f, 0.f, 0.f, 0.f};

#pragma unroll
    for (int rb = 0; rb < 4; ++rb) {
        const int arow = rg * 64 + rb * 16 + li;
#pragma unroll
        for (int ks = 0; ks < 4; ++ks) {
            const int idx = arow * 128 + (((ks * 4 + lg) ^ (arow & 7)) * 8);
            f16x8 Ah = *reinterpret_cast<const f16x8*>(&Xs[idx]);
            f16x8 Al = *reinterpret_cast<const f16x8*>(&Xs[16384 + idx]);
#pragma unroll
            for (int cb = 0; cb < 2; ++cb) {
                acc[rb][cb] = __builtin_amdgcn_mfma_f32_16x16x32_f16(Ah, Bh[cb][ks], acc[rb][cb], 0, 0, 0);
                acc[rb][cb] = __builtin_amdgcn_mfma_f32_16x16x32_f16(Ah, Bl[cb][ks], acc[rb][cb], 0, 0, 0);
                acc[rb][cb] = __builtin_amdgcn_mfma_f32_16x16x32_f16(Al, Bh[cb][ks], acc[rb][cb], 0, 0, 0);
            }
        }
    }

    // epilogue: D col = lane&15, row = (lane>>4)*4 + reg; scale by dinv, store f16
#pragma unroll
    for (int rb = 0; rb < 4; ++rb) {
#pragma unroll
        for (int r = 0; r < 4; ++r) {
            const int grow = row0 + rg * 64 + rb * 16 + lg * 4 + r;
            if (grow < N) {
                const float d = dinv[grow];
#pragma unroll
                for (int cb = 0; cb < 2; ++cb)
                    H[(size_t)grow * HID + cg * 32 + cb * 16 + li] = (f16)(acc[rb][cb][r] * d);
            }
        }
    }
}

// ================= aggregation (f16 gather, unroll 8) =================
// lane owns 2 cols via one uint load; out = di*(h'_self + sum_j h'_j) + b

__global__ __launch_bounds__(256) void k_agg_csr(const f16* __restrict__ h,
                                                 const int* __restrict__ csr_src,
                                                 const int* __restrict__ row_ptr,
                                                 const float* __restrict__ dinv,
                                                 const float* __restrict__ bias,
                                                 float* __restrict__ out, int N) {
    int node = (blockIdx.x * 256 + threadIdx.x) >> 6;
    if (node >= N) return;
    int lane = threadIdx.x & 63;
    const unsigned int* h32 = reinterpret_cast<const unsigned int*>(h);  // row = 64 uints

    float2 self = h2f(h32[(size_t)node * 64 + lane]);
    float accx = self.x, accy = self.y;

    int j = row_ptr[node];
    const int end = row_ptr[node + 1];

    for (; j + 8 <= end; j += 8) {
        int s0 = csr_src[j];
        int s1 = csr_src[j + 1];
        int s2 = csr_src[j + 2];
        int s3 = csr_src[j + 3];
        int s4 = csr_src[j + 4];
        int s5 = csr_src[j + 5];
        int s6 = csr_src[j + 6];
        int s7 = csr_src[j + 7];
        unsigned int u0 = h32[(size_t)s0 * 64 + lane];
        unsigned int u1 = h32[(size_t)s1 * 64 + lane];
        unsigned int u2 = h32[(size_t)s2 * 64 + lane];
        unsigned int u3 = h32[(size_t)s3 * 64 + lane];
        unsigned int u4 = h32[(size_t)s4 * 64 + lane];
        unsigned int u5 = h32[(size_t)s5 * 64 + lane];
        unsigned int u6 = h32[(size_t)s6 * 64 + lane];
        unsigned int u7 = h32[(size_t)s7 * 64 + lane];
        float2 v0 = h2f(u0), v1 = h2f(u1), v2 = h2f(u2), v3 = h2f(u3);
        float2 v4 = h2f(u4), v5 = h2f(u5), v6 = h2f(u6), v7 = h2f(u7);
        accx += ((v0.x + v1.x) + (v2.x + v3.x)) + ((v4.x + v5.x) + (v6.x + v7.x));
        accy += ((v0.y + v1.y) + (v2.y + v3.y)) + ((v4.y + v5.y) + (v6.y + v7.y));
    }
    for (; j < end; ++j) {
        float2 v = h2f(h32[(size_t)csr_src[j] * 64 + lane]);
        accx += v.x;
        accy += v.y;
    }

    float di = dinv[node];
    int c = lane * 2;
    float2 o;
    o.x = fmaf(di, accx, bias[c]);
    o.y = fmaf(di, accy, bias[c + 1]);
    *reinterpret_cast<float2*>(out + (size_t)node * HID + c) = o;
}

// ================= launch =================

extern "C" void kernel_launch(void* const* d_in, const int* in_sizes, int n_in,
                              void* d_out, int out_size, void* d_ws, size_t ws_size,
                              hipStream_t stream) {
    const float* x  = (const float*)d_in[0];
    const int*   ei = (const int*)  d_in[1];
    const float* W0 = (const float*)d_in[2];
    const float* b0 = (const float*)d_in[3];
    const float* W1 = (const float*)d_in[4];
    const float* b1 = (const float*)d_in[5];
    const float* W2 = (const float*)d_in[6];
    const float* b2 = (const float*)d_in[7];

    const int N = in_sizes[0] / HID;
    const int E = in_sizes[1] / 2;
    const int* row = ei;        // sources
    const int* col = ei + E;    // destinations

    const int nb_n = (N + 255) / 256;

    // workspace layout
    f16*   h16     = (f16*)d_ws;                      // [N,128] f16 (= h', dinv-scaled)
    float* dinv    = (float*)(h16 + (size_t)N * HID); // [N]
    int*   cnt     = (int*)(dinv + N);                // [N]
    int*   row_ptr = cnt + N;                         // [N+1]
    int*   fill    = row_ptr + (N + 1);               // [N]
    int*   bsum    = fill + N;                        // [nb_n]
    int*   csr_src = bsum + nb_n;                     // [E]
    f16*   wt0     = (f16*)(csr_src + E);             // [32768] each
    f16*   wt1     = wt0 + 32768;
    f16*   wt2     = wt1 + 32768;
    float* out     = (float*)d_out;                   // [N,128]

    const int nb_e    = (E + 255) / 256;
    const int nb_gemm = (N + BR - 1) / BR;
    const int nb_agg  = (N * 64 + 255) / 256;
    const int nb_fill = ((E + FILL_CHUNK - 1) / FILL_CHUNK) * 8;

    // ---- CSR build + W prep ----
    hipMemsetAsync(cnt, 0, (size_t)N * sizeof(int), stream);
    k_wprep<<<16, 256, 0, stream>>>(W0, wt0);
    k_wprep<<<16, 256, 0, stream>>>(W1, wt1);
    k_wprep<<<16, 256, 0, stream>>>(W2, wt2);
    k_deg_count <<<nb_e, 256, 0, stream>>>(col, cnt, E);
    k_scan_block<<<nb_n, 256, 0, stream>>>(cnt, row_ptr, bsum, dinv, N);
    k_scan_bsum <<<1, 1024, 0, stream>>>(bsum, nb_n);
    k_scan_add  <<<nb_n, 256, 0, stream>>>(row_ptr, bsum, fill, N, E);
    k_fill      <<<nb_fill, 256, 0, stream>>>(row, col, fill, csr_src, E, N);

    // ---- layer 0 ----
    k_gemm   <<<nb_gemm, 512, 0, stream>>>(x, wt0, dinv, h16, N, 0);
    k_agg_csr<<<nb_agg, 256, 0, stream>>>(h16, csr_src, row_ptr, dinv, b0, out, N);
    // ---- layer 1 ----
    k_gemm   <<<nb_gemm, 512, 0, stream>>>(out, wt1, dinv, h16, N, 1);
    k_agg_csr<<<nb_agg, 256, 0, stream>>>(h16, csr_src, row_ptr, dinv, b1, out, N);
    // ---- layer 2 ----
    k_gemm   <<<nb_gemm, 512, 0, stream>>>(out, wt2, dinv, h16, N, 1);
    k_agg_csr<<<nb_agg, 256, 0, stream>>>(h16, csr_src, row_ptr, dinv, b2, out, N);
}